// Round 6
// baseline (180.424 us; speedup 1.0000x reference)
//
#include <hip/hip_runtime.h>
#include <hip/hip_bf16.h>

// R6: DRAM-streaming restructure.
//  Diagnosis: all prior versions read x as 128-256B chunks at 12.5KB channel
//  stride -> DRAM row-activation bound (~2 TB/s, 51us for 103MB). Fix: one
//  wave streams one whole channel plane (12.5KB contiguous).
//  stage1: block=(b, channel-octet), 8 waves x 1 channel. BN scale/shift are
//    wave-uniform scalars; zero LDS, zero barriers. Pool pairs from float4
//    row-pairs; write y bf16 directly in MFMA fragment order (block's 8 waves
//    jointly cover each 16B fragment slot). W-swizzle rides in the same grid.
//  stage2: R4's zero-LDS zero-barrier fragment GEMM (ysw/wsw L2/L3-warm).

typedef short bf16x8 __attribute__((ext_vector_type(8)));
typedef float f32x4  __attribute__((ext_vector_type(4)));

constexpr int BB=16, CIN=512, COUT=256, HH=56, WW=56, HP=28, WP=28;
constexpr int PP      = HP * WP;            // 784 pooled pixels per plane
constexpr int NPAIR   = PP / 2;             // 392 pooled-column pairs
constexpr int MTILES  = BB * PP / 16;       // 784
constexpr int XBLOCKS = BB * (CIN / 8);     // 1024 (b x channel-octet)
constexpr int WBLOCKS = (COUT * CIN / 8) / 512;  // 32

__device__ __forceinline__ short f2bf(float f) {
    __hip_bfloat16 h = __float2bfloat16(f);
    return *reinterpret_cast<short*>(&h);
}

// Fragment-order layouts (consumed by stage2; verified R2-R5):
//   wsw[(ot*16+ksg)*64 + lane] : W[o=ot*16+(lane&15)][k=ksg*32+(lane>>4)*8+j]
//   ysw[(mt*16+ksg)*64 + lane] : y[m=mt*16+(lane&15)][k=ksg*32+(lane>>4)*8+j]

__global__ __launch_bounds__(512)
void stage1(const float* __restrict__ x,  const float* __restrict__ bnw,
            const float* __restrict__ bnb, const float* __restrict__ bnm,
            const float* __restrict__ bnv, const float* __restrict__ w,
            short* __restrict__ ysw, short* __restrict__ wsw)
{
    const int tid = threadIdx.x;
    const int blk = blockIdx.x;

    if (blk >= XBLOCKS) {
        // ---- W swizzle path (32 blocks x 512 thr) ----
        int t    = (blk - XBLOCKS) * 512 + tid;      // [0, 16384)
        int lane = t & 63;
        int tile = t >> 6;                           // ot*16 + ksg
        int o    = (tile >> 4) * 16 + (lane & 15);
        int k    = (tile & 15) * 32 + (lane >> 4) * 8;
        const float4* src = reinterpret_cast<const float4*>(w + (size_t)o * CIN + k);
        float4 v0 = src[0], v1 = src[1];
        bf16x8 p;
        p[0]=f2bf(v0.x); p[1]=f2bf(v0.y); p[2]=f2bf(v0.z); p[3]=f2bf(v0.w);
        p[4]=f2bf(v1.x); p[5]=f2bf(v1.y); p[6]=f2bf(v1.z); p[7]=f2bf(v1.w);
        reinterpret_cast<bf16x8*>(wsw)[t] = p;
        return;
    }

    // ---- x streaming path: wave w8 streams channel c = oct*8+w8, image b ----
    const int b    = blk >> 6;
    const int oct  = blk & 63;
    const int w8   = tid >> 6;           // wave id == byte-pair j within slot
    const int lane = tid & 63;
    const int c    = oct * 8 + w8;

    const float sc = bnw[c] * rsqrtf(bnv[c] + 1e-5f);
    const float tc = bnb[c] - bnm[c] * sc;

    const float4* xp = reinterpret_cast<const float4*>(x)
                     + ((size_t)b * CIN + c) * (HH * WW / 4);

    // preload the lane's entire plane share: 7 float4 row-pairs, all in flight
    float4 v0[7], v1[7];
    #pragma unroll
    for (int it = 0; it < 7; it++) {
        int p2  = it * 64 + lane;
        int p2c = p2 < NPAIR ? p2 : NPAIR - 1;       // clamp tail (dup load)
        int hp  = p2c / 14;                          // 14 float4 per raw row
        int wpp = p2c % 14;
        int i0  = (2 * hp) * 14 + wpp;
        v0[it] = xp[i0];                             // raw row 2hp
        v1[it] = xp[i0 + 14];                        // raw row 2hp+1
    }

    const int ksg = oct >> 2;            // k-subgroup of this channel octet
    const int q   = oct & 3;             // lane-quad within slot

    #pragma unroll
    for (int it = 0; it < 7; it++) {
        int p2 = it * 64 + lane;
        if (p2 < NPAIR) {
            float a0 = fmaxf(fmaf(v0[it].x, sc, tc), 0.f);
            float a1 = fmaxf(fmaf(v0[it].y, sc, tc), 0.f);
            float a2 = fmaxf(fmaf(v0[it].z, sc, tc), 0.f);
            float a3 = fmaxf(fmaf(v0[it].w, sc, tc), 0.f);
            float b0 = fmaxf(fmaf(v1[it].x, sc, tc), 0.f);
            float b1 = fmaxf(fmaf(v1[it].y, sc, tc), 0.f);
            float b2 = fmaxf(fmaf(v1[it].z, sc, tc), 0.f);
            float b3 = fmaxf(fmaf(v1[it].w, sc, tc), 0.f);
            float y0 = (a0 + a1 + b0 + b1) * 0.25f;  // pooled col 2*wpp
            float y1 = (a2 + a3 + b2 + b3) * 0.25f;  // pooled col 2*wpp+1

            int m0 = b * PP + 2 * p2;                // even -> m0&15 <= 14
            int slot = ((m0 >> 4) * 16 + ksg) * 64 + q * 16 + (m0 & 15);
            ysw[(size_t)slot * 8 + w8]       = f2bf(y0);
            ysw[(size_t)(slot + 1) * 8 + w8] = f2bf(y1);
        }
    }
}

__global__ __launch_bounds__(256)
void stage2(const short* __restrict__ ysw, const short* __restrict__ wsw,
            float* __restrict__ out)
{
    const int mt   = blockIdx.x;         // 0..783
    const int tid  = threadIdx.x;
    const int lane = tid & 63;
    const int wv   = tid >> 6;           // wave -> 64 outputs
    const int l16  = lane & 15;
    const int q    = lane >> 4;

    const bf16x8* yfp = reinterpret_cast<const bf16x8*>(ysw);
    const bf16x8* wfp = reinterpret_cast<const bf16x8*>(wsw);

    f32x4 acc[4];
    #pragma unroll
    for (int i = 0; i < 4; i++) acc[i] = (f32x4){0.f, 0.f, 0.f, 0.f};

    #pragma unroll
    for (int ksg = 0; ksg < 16; ksg++) {
        bf16x8 yf = yfp[(mt * 16 + ksg) * 64 + lane];
        #pragma unroll
        for (int ns = 0; ns < 4; ns++) {
            bf16x8 wf = wfp[((wv * 4 + ns) * 16 + ksg) * 64 + lane];
            acc[ns] = __builtin_amdgcn_mfma_f32_16x16x32_bf16(wf, yf, acc[ns], 0, 0, 0);
        }
    }

    // epilogue: D col = m = l16 -> m-contiguous stores
    const int m = mt * 16 + l16;
    const int b = m / PP;
    const int r = m % PP;
    const int addrm = b * (COUT * PP) + r;
    #pragma unroll
    for (int ns = 0; ns < 4; ns++)
        #pragma unroll
        for (int rg = 0; rg < 4; rg++) {
            int o = wv * 64 + ns * 16 + q * 4 + rg;
            out[(size_t)addrm + (size_t)o * PP] = acc[ns][rg];
        }
}

extern "C" void kernel_launch(void* const* d_in, const int* in_sizes, int n_in,
                              void* d_out, int out_size, void* d_ws, size_t ws_size,
                              hipStream_t stream) {
    const float* x   = (const float*)d_in[0];
    const float* bnw = (const float*)d_in[1];
    const float* bnb = (const float*)d_in[2];
    const float* bnm = (const float*)d_in[3];
    const float* bnv = (const float*)d_in[4];
    const float* w   = (const float*)d_in[5];
    float* out = (float*)d_out;

    short* wsw = (short*)d_ws;                         // 256 KB
    short* ysw = (short*)d_ws + (size_t)COUT * CIN;    // 12.8 MB

    stage1<<<XBLOCKS + WBLOCKS, 512, 0, stream>>>(x, bnw, bnb, bnm, bnv, w, ysw, wsw);
    stage2<<<MTILES, 256, 0, stream>>>(ysw, wsw, out);
}

// Round 7
// 173.295 us; speedup vs baseline: 1.0411x; 1.0411x over previous
//
#include <hip/hip_runtime.h>
#include <hip/hip_bf16.h>

// R7: LDS-transpose structure — both global directions coalesced.
//  Diagnosis of R2-R6 plateau: every version had a 64-lane scatter/gather on
//  one side of the pixel<->channel transpose (R2-R5: 64x8B read gather at
//  1.7 TB/s; R6: 64x2B write scatter). Fix: do the transpose in LDS.
//  stage1: block=(b, 16-ch slab), 8 waves. Phase A: wave streams 2 channel
//    planes contiguously, pools in regs, writes packed bf16 pairs to LDS
//    [16][790] (conflict-free). One barrier. Phase B: lane reads 8 channels
//    of one pixel from LDS (ds_read_u16, <=2-way), stores ysw in fragment
//    order as contiguous 512B segments. W-swizzle rides in the same grid.
//  stage2: fragment GEMM, 2 m-tiles/block (halves W L2 traffic vs R4).

typedef short bf16x8 __attribute__((ext_vector_type(8)));
typedef float f32x4  __attribute__((ext_vector_type(4)));

constexpr int BB=16, CIN=512, COUT=256, HH=56, WW=56, HP=28, WP=28;
constexpr int PP      = HP * WP;                 // 784 pooled px per plane
constexpr int NPAIR   = PP / 2;                  // 392 pooled-col pairs
constexpr int PP_PAD  = 790;                     // LDS row pad (bank spread)
constexpr int MTILES  = BB * PP / 16;            // 784
constexpr int XBLOCKS = BB * 32;                 // 512 (b x 16-ch slab)
constexpr int WBLOCKS = (COUT * CIN / 8) / 512;  // 32

__device__ __forceinline__ short f2bf(float f) {
    __hip_bfloat16 h = __float2bfloat16(f);
    return *reinterpret_cast<short*>(&h);
}

// Fragment-order layouts (consumed by stage2; verified R2-R6):
//   wsw[(ot*16+ksg)*64 + lane] : W[o=ot*16+(lane&15)][k=ksg*32+(lane>>4)*8+j]
//   ysw[(mt*16+ksg)*64 + lane] : y[m=mt*16+(lane&15)][k=ksg*32+(lane>>4)*8+j]

__global__ __launch_bounds__(512)
void stage1(const float* __restrict__ x,  const float* __restrict__ bnw,
            const float* __restrict__ bnb, const float* __restrict__ bnm,
            const float* __restrict__ bnv, const float* __restrict__ w,
            short* __restrict__ ysw, short* __restrict__ wsw)
{
    const int tid = threadIdx.x;
    const int blk = blockIdx.x;

    if (blk >= XBLOCKS) {
        // ---- W swizzle path (32 blocks x 512 thr) ----
        int t    = (blk - XBLOCKS) * 512 + tid;      // [0, 16384)
        int lane = t & 63;
        int tile = t >> 6;                           // ot*16 + ksg
        int o    = (tile >> 4) * 16 + (lane & 15);
        int k    = (tile & 15) * 32 + (lane >> 4) * 8;
        const float4* src = reinterpret_cast<const float4*>(w + (size_t)o * CIN + k);
        float4 v0 = src[0], v1 = src[1];
        bf16x8 p;
        p[0]=f2bf(v0.x); p[1]=f2bf(v0.y); p[2]=f2bf(v0.z); p[3]=f2bf(v0.w);
        p[4]=f2bf(v1.x); p[5]=f2bf(v1.y); p[6]=f2bf(v1.z); p[7]=f2bf(v1.w);
        reinterpret_cast<bf16x8*>(wsw)[t] = p;
        return;
    }

    __shared__ __align__(16) short Ylds[16 * PP_PAD];   // 25.3 KB pooled slab

    const int b    = blk >> 5;           // image
    const int sub  = blk & 31;
    const int ksg  = sub >> 1;           // k-subgroup (32 channels)
    const int half = sub & 1;            // which 16-channel half
    const int c0   = ksg * 32 + half * 16;

    const int wv   = tid >> 6;           // 0..7
    const int lane = tid & 63;

    // ---- Phase A: stream 2 channel planes per wave, pool, LDS ----
    const int cA  = c0 + wv * 2;
    const int cB  = cA + 1;
    const float sA = bnw[cA] * rsqrtf(bnv[cA] + 1e-5f);
    const float tA = bnb[cA] - bnm[cA] * sA;
    const float sB = bnw[cB] * rsqrtf(bnv[cB] + 1e-5f);
    const float tB = bnb[cB] - bnm[cB] * sB;

    const float4* xpA = reinterpret_cast<const float4*>(x)
                      + ((size_t)b * CIN + cA) * (HH * WW / 4);
    const float4* xpB = xpA + (HH * WW / 4);

    int i0[7];
    float4 a0[7], a1[7], b0[7], b1[7];
    #pragma unroll
    for (int it = 0; it < 7; it++) {
        int p2  = it * 64 + lane;
        int p2c = p2 < NPAIR ? p2 : NPAIR - 1;   // clamp tail (dup load)
        int hp  = p2c / 14;                      // 14 float4 per raw row
        i0[it]  = p2c + 14 * hp;                 // = (2hp)*14 + (p2c%14)
        a0[it] = xpA[i0[it]];
        a1[it] = xpA[i0[it] + 14];
    }
    #pragma unroll
    for (int it = 0; it < 7; it++) {
        b0[it] = xpB[i0[it]];
        b1[it] = xpB[i0[it] + 14];
    }

    uint* Yu = reinterpret_cast<uint*>(Ylds);
    const int clA = wv * 2, clB = clA + 1;
    #pragma unroll
    for (int it = 0; it < 7; it++) {
        int p2 = it * 64 + lane;
        if (p2 < NPAIR) {
            float y0 = (fmaxf(fmaf(a0[it].x, sA, tA), 0.f) + fmaxf(fmaf(a0[it].y, sA, tA), 0.f)
                      + fmaxf(fmaf(a1[it].x, sA, tA), 0.f) + fmaxf(fmaf(a1[it].y, sA, tA), 0.f)) * 0.25f;
            float y1 = (fmaxf(fmaf(a0[it].z, sA, tA), 0.f) + fmaxf(fmaf(a0[it].w, sA, tA), 0.f)
                      + fmaxf(fmaf(a1[it].z, sA, tA), 0.f) + fmaxf(fmaf(a1[it].w, sA, tA), 0.f)) * 0.25f;
            uint u = (uint)(unsigned short)f2bf(y0) | ((uint)(unsigned short)f2bf(y1) << 16);
            Yu[clA * (PP_PAD / 2) + p2] = u;
        }
    }
    #pragma unroll
    for (int it = 0; it < 7; it++) {
        int p2 = it * 64 + lane;
        if (p2 < NPAIR) {
            float y0 = (fmaxf(fmaf(b0[it].x, sB, tB), 0.f) + fmaxf(fmaf(b0[it].y, sB, tB), 0.f)
                      + fmaxf(fmaf(b1[it].x, sB, tB), 0.f) + fmaxf(fmaf(b1[it].y, sB, tB), 0.f)) * 0.25f;
            float y1 = (fmaxf(fmaf(b0[it].z, sB, tB), 0.f) + fmaxf(fmaf(b0[it].w, sB, tB), 0.f)
                      + fmaxf(fmaf(b1[it].z, sB, tB), 0.f) + fmaxf(fmaf(b1[it].w, sB, tB), 0.f)) * 0.25f;
            uint u = (uint)(unsigned short)f2bf(y0) | ((uint)(unsigned short)f2bf(y1) << 16);
            Yu[clB * (PP_PAD / 2) + p2] = u;
        }
    }
    __syncthreads();                     // sole barrier

    // ---- Phase B: LDS -> fragment-order ysw (contiguous 512B segments) ----
    // fragments for this block: 49 m-tiles x 32 lanes (this half's quads)
    bf16x8* yswv = reinterpret_cast<bf16x8*>(ysw);
    for (int f = tid; f < 49 * 32; f += 512) {
        int mtl    = f >> 5;             // m-tile within plane, 0..48
        int lane32 = f & 31;
        int qloc   = lane32 >> 4;        // 0..1
        int l16    = lane32 & 15;
        int px     = mtl * 16 + l16;     // pooled pixel in plane
        bf16x8 p;
        #pragma unroll
        for (int j = 0; j < 8; j++)
            p[j] = Ylds[(qloc * 8 + j) * PP_PAD + px];
        int mt     = b * 49 + mtl;
        int lane64 = (half * 2 + qloc) * 16 + l16;
        yswv[(size_t)(mt * 16 + ksg) * 64 + lane64] = p;
    }
}

__global__ __launch_bounds__(256)
void stage2(const short* __restrict__ ysw, const short* __restrict__ wsw,
            float* __restrict__ out)
{
    const int mt0  = blockIdx.x * 2;     // 2 m-tiles per block
    const int tid  = threadIdx.x;
    const int lane = tid & 63;
    const int wv   = tid >> 6;           // wave -> 64 outputs
    const int l16  = lane & 15;
    const int q    = lane >> 4;

    const bf16x8* yfp = reinterpret_cast<const bf16x8*>(ysw);
    const bf16x8* wfp = reinterpret_cast<const bf16x8*>(wsw);

    f32x4 acc[2][4];
    #pragma unroll
    for (int t = 0; t < 2; t++)
        #pragma unroll
        for (int i = 0; i < 4; i++) acc[t][i] = (f32x4){0.f, 0.f, 0.f, 0.f};

    #pragma unroll
    for (int ksg = 0; ksg < 16; ksg++) {
        bf16x8 yf0 = yfp[(size_t)(mt0 * 16 + ksg) * 64 + lane];
        bf16x8 yf1 = yfp[(size_t)((mt0 + 1) * 16 + ksg) * 64 + lane];
        #pragma unroll
        for (int ns = 0; ns < 4; ns++) {
            bf16x8 wf = wfp[(size_t)((wv * 4 + ns) * 16 + ksg) * 64 + lane];
            acc[0][ns] = __builtin_amdgcn_mfma_f32_16x16x32_bf16(wf, yf0, acc[0][ns], 0, 0, 0);
            acc[1][ns] = __builtin_amdgcn_mfma_f32_16x16x32_bf16(wf, yf1, acc[1][ns], 0, 0, 0);
        }
    }

    // epilogue: D col = m = l16 -> m-contiguous stores
    #pragma unroll
    for (int t = 0; t < 2; t++) {
        const int m = (mt0 + t) * 16 + l16;
        const int b = m / PP;
        const int r = m % PP;
        const int addrm = b * (COUT * PP) + r;
        #pragma unroll
        for (int ns = 0; ns < 4; ns++)
            #pragma unroll
            for (int rg = 0; rg < 4; rg++) {
                int o = wv * 64 + ns * 16 + q * 4 + rg;
                out[(size_t)addrm + (size_t)o * PP] = acc[t][ns][rg];
            }
    }
}

extern "C" void kernel_launch(void* const* d_in, const int* in_sizes, int n_in,
                              void* d_out, int out_size, void* d_ws, size_t ws_size,
                              hipStream_t stream) {
    const float* x   = (const float*)d_in[0];
    const float* bnw = (const float*)d_in[1];
    const float* bnb = (const float*)d_in[2];
    const float* bnm = (const float*)d_in[3];
    const float* bnv = (const float*)d_in[4];
    const float* w   = (const float*)d_in[5];
    float* out = (float*)d_out;

    short* wsw = (short*)d_ws;                         // 256 KB
    short* ysw = (short*)d_ws + (size_t)COUT * CIN;    // 12.8 MB

    stage1<<<XBLOCKS + WBLOCKS, 512, 0, stream>>>(x, bnw, bnb, bnm, bnv, w, ysw, wsw);
    stage2<<<MTILES / 2, 256, 0, stream>>>(ysw, wsw, out);
}

// Round 8
// 172.544 us; speedup vs baseline: 1.0457x; 1.0044x over previous
//
#include <hip/hip_runtime.h>
#include <hip/hip_bf16.h>

// R8: occupancy-rich streaming stage1 (discriminates hypothesis A vs B).
//  stage1: block = (image b, 8-channel group g), 512 thr = 8 waves, one wave
//    streams ONE channel plane (contiguous 224B segments), pools in regs,
//    conflict-free LDS transpose (12.7 KB, packed uint writes), one barrier,
//    then fragment-order ysw stores in contiguous 256B runs. VGPR ~80,
//    ~3 blocks/CU co-resident, 1024 blocks = 4 full grid rounds.
//  stage2: R7's proven zero-LDS zero-barrier fragment GEMM (unchanged).

typedef short bf16x8 __attribute__((ext_vector_type(8)));
typedef float f32x4  __attribute__((ext_vector_type(4)));

constexpr int BB=16, CIN=512, COUT=256, HH=56, WW=56, HP=28, WP=28;
constexpr int PP      = HP * WP;                 // 784 pooled px per plane
constexpr int NPAIR   = PP / 2;                  // 392 pooled-col pairs
constexpr int PADU    = 396;                     // uints per LDS channel row
constexpr int MTILES  = BB * PP / 16;            // 784
constexpr int XBLOCKS = BB * (CIN / 8);          // 1024 (b x 8-ch group)
constexpr int WBLOCKS = (COUT * CIN / 8) / 512;  // 32

__device__ __forceinline__ short f2bf(float f) {
    __hip_bfloat16 h = __float2bfloat16(f);
    return *reinterpret_cast<short*>(&h);
}

// Fragment-order layouts (consumed by stage2; verified R2-R7):
//   wsw[(ot*16+ksg)*64 + lane] : W[o=ot*16+(lane&15)][k=ksg*32+(lane>>4)*8+j]
//   ysw[(mt*16+ksg)*64 + lane] : y[m=mt*16+(lane&15)][k=ksg*32+(lane>>4)*8+j]

__global__ __launch_bounds__(512)
void stage1(const float* __restrict__ x,  const float* __restrict__ bnw,
            const float* __restrict__ bnb, const float* __restrict__ bnm,
            const float* __restrict__ bnv, const float* __restrict__ w,
            short* __restrict__ ysw, short* __restrict__ wsw)
{
    const int tid = threadIdx.x;
    const int blk = blockIdx.x;

    if (blk >= XBLOCKS) {
        // ---- W swizzle path (32 blocks x 512 thr) ----
        int t    = (blk - XBLOCKS) * 512 + tid;      // [0, 16384)
        int lane = t & 63;
        int tile = t >> 6;                           // ot*16 + ksg
        int o    = (tile >> 4) * 16 + (lane & 15);
        int k    = (tile & 15) * 32 + (lane >> 4) * 8;
        const float4* src = reinterpret_cast<const float4*>(w + (size_t)o * CIN + k);
        float4 v0 = src[0], v1 = src[1];
        bf16x8 p;
        p[0]=f2bf(v0.x); p[1]=f2bf(v0.y); p[2]=f2bf(v0.z); p[3]=f2bf(v0.w);
        p[4]=f2bf(v1.x); p[5]=f2bf(v1.y); p[6]=f2bf(v1.z); p[7]=f2bf(v1.w);
        reinterpret_cast<bf16x8*>(wsw)[t] = p;
        return;
    }

    __shared__ uint Yu[8 * PADU];        // 12.7 KB: [local ch j][packed p2]

    const int b    = blk >> 6;           // image
    const int g    = blk & 63;           // 8-channel group: c in [g*8, g*8+8)
    const int wv   = tid >> 6;           // wave = local channel j, 0..7
    const int lane = tid & 63;
    const int c    = g * 8 + wv;

    const float sc = bnw[c] * rsqrtf(bnv[c] + 1e-5f);
    const float tc = bnb[c] - bnm[c] * sc;

    const float4* xp = reinterpret_cast<const float4*>(x)
                     + ((size_t)b * CIN + c) * (HH * WW / 4);

    // ---- Phase A: wave streams its whole plane; pool; LDS (conflict-free) --
    #pragma unroll
    for (int r = 0; r < 7; r++) {
        int p2 = r * 64 + lane;
        if (p2 < NPAIR) {
            int hp = p2 / 14;            // 14 float4 per raw row
            int i0 = p2 + 14 * hp;       // = (2hp)*14 + (p2%14)
            float4 v0 = xp[i0];          // raw row 2hp
            float4 v1 = xp[i0 + 14];     // raw row 2hp+1
            float y0 = (fmaxf(fmaf(v0.x, sc, tc), 0.f) + fmaxf(fmaf(v0.y, sc, tc), 0.f)
                      + fmaxf(fmaf(v1.x, sc, tc), 0.f) + fmaxf(fmaf(v1.y, sc, tc), 0.f)) * 0.25f;
            float y1 = (fmaxf(fmaf(v0.z, sc, tc), 0.f) + fmaxf(fmaf(v0.w, sc, tc), 0.f)
                      + fmaxf(fmaf(v1.z, sc, tc), 0.f) + fmaxf(fmaf(v1.w, sc, tc), 0.f)) * 0.25f;
            uint u = (uint)(unsigned short)f2bf(y0) | ((uint)(unsigned short)f2bf(y1) << 16);
            Yu[wv * PADU + p2] = u;      // lane-stride 4B: conflict-free
        }
    }
    __syncthreads();                     // sole barrier

    // ---- Phase B: LDS -> fragment-order ysw (contiguous 256B runs) ----
    const short* Ys = reinterpret_cast<const short*>(Yu);  // row = 792 shorts
    const int ksg = g >> 2;              // this group's k-subgroup
    const int q   = g & 3;               // lane-quad within fragment slot
    bf16x8* yswv = reinterpret_cast<bf16x8*>(ysw);
    for (int f = tid; f < PP; f += 512) {
        int mtl = f >> 4;                // m-tile within plane, 0..48
        int l16 = f & 15;
        bf16x8 p;
        #pragma unroll
        for (int j = 0; j < 8; j++)
            p[j] = Ys[j * (2 * PADU) + f];   // 2 lanes/dword: no conflict
        yswv[(size_t)((b * 49 + mtl) * 16 + ksg) * 64 + q * 16 + l16] = p;
    }
}

__global__ __launch_bounds__(256)
void stage2(const short* __restrict__ ysw, const short* __restrict__ wsw,
            float* __restrict__ out)
{
    const int mt0  = blockIdx.x * 2;     // 2 m-tiles per block
    const int tid  = threadIdx.x;
    const int lane = tid & 63;
    const int wv   = tid >> 6;           // wave -> 64 outputs
    const int l16  = lane & 15;
    const int q    = lane >> 4;

    const bf16x8* yfp = reinterpret_cast<const bf16x8*>(ysw);
    const bf16x8* wfp = reinterpret_cast<const bf16x8*>(wsw);

    f32x4 acc[2][4];
    #pragma unroll
    for (int t = 0; t < 2; t++)
        #pragma unroll
        for (int i = 0; i < 4; i++) acc[t][i] = (f32x4){0.f, 0.f, 0.f, 0.f};

    #pragma unroll
    for (int ksg = 0; ksg < 16; ksg++) {
        bf16x8 yf0 = yfp[(size_t)(mt0 * 16 + ksg) * 64 + lane];
        bf16x8 yf1 = yfp[(size_t)((mt0 + 1) * 16 + ksg) * 64 + lane];
        #pragma unroll
        for (int ns = 0; ns < 4; ns++) {
            bf16x8 wf = wfp[(size_t)((wv * 4 + ns) * 16 + ksg) * 64 + lane];
            acc[0][ns] = __builtin_amdgcn_mfma_f32_16x16x32_bf16(wf, yf0, acc[0][ns], 0, 0, 0);
            acc[1][ns] = __builtin_amdgcn_mfma_f32_16x16x32_bf16(wf, yf1, acc[1][ns], 0, 0, 0);
        }
    }

    // epilogue: D col = m = l16 -> m-contiguous stores
    #pragma unroll
    for (int t = 0; t < 2; t++) {
        const int m = (mt0 + t) * 16 + l16;
        const int b = m / PP;
        const int r = m % PP;
        const int addrm = b * (COUT * PP) + r;
        #pragma unroll
        for (int ns = 0; ns < 4; ns++)
            #pragma unroll
            for (int rg = 0; rg < 4; rg++) {
                int o = wv * 64 + ns * 16 + q * 4 + rg;
                out[(size_t)addrm + (size_t)o * PP] = acc[t][ns][rg];
            }
    }
}

extern "C" void kernel_launch(void* const* d_in, const int* in_sizes, int n_in,
                              void* d_out, int out_size, void* d_ws, size_t ws_size,
                              hipStream_t stream) {
    const float* x   = (const float*)d_in[0];
    const float* bnw = (const float*)d_in[1];
    const float* bnb = (const float*)d_in[2];
    const float* bnm = (const float*)d_in[3];
    const float* bnv = (const float*)d_in[4];
    const float* w   = (const float*)d_in[5];
    float* out = (float*)d_out;

    short* wsw = (short*)d_ws;                         // 256 KB
    short* ysw = (short*)d_ws + (size_t)COUT * CIN;    // 12.8 MB

    stage1<<<XBLOCKS + WBLOCKS, 512, 0, stream>>>(x, bnw, bnb, bnm, bnv, w, ysw, wsw);
    stage2<<<MTILES / 2, 256, 0, stream>>>(ysw, wsw, out);
}